// Round 16
// baseline (1220.623 us; speedup 1.0000x reference)
//
#include <hip/hip_runtime.h>
#include <hip/hip_cooperative_groups.h>
#include <math.h>

namespace cg = cooperative_groups;

#define NN 50000
#define NE 800000
#define ET 850000   // NE + NN self loops
#define HCC 256     // H*C
#define GG 256
#define CAP 64      // fixed bucket capacity per node
#define NB 16       // BN stat buckets

// ---------------- workspace layout (float-element offsets) ----------------
constexpr size_t NHC    = (size_t)NN * HCC;
constexpr size_t O_H    = 0;                         // bf16 h [NN,256]
constexpr size_t O_AGG  = O_H + NHC / 2;             // bf16 agg [NN,256]
constexpr size_t O_REC  = O_AGG + NHC / 2;           // uint4 rec [NN*64]
constexpr size_t O_BT0  = O_REC + (size_t)NN * CAP * 4;
constexpr size_t O_BT1  = O_BT0 + 16384;
constexpr size_t O_BT2  = O_BT1 + 32768;
constexpr size_t O_AS   = O_BT2 + 32768;             // [NN,4]
constexpr size_t O_AD   = O_AS + (size_t)NN * 4;     // [NN,4]
constexpr size_t O_M    = O_AD + (size_t)NN * 4;     // [16,4]
// ---- zero zone (zeroed in phase 1) ----
constexpr size_t O_ZERO = O_M + 64;
constexpr size_t O_DEG  = O_ZERO;                    // int [NN]
constexpr size_t O_SLS  = O_DEG + NN;                // [4]
constexpr size_t O_PART = O_SLS + 4;                 // [3][NB][512]
constexpr size_t O_END  = O_PART + 3 * NB * 512;
constexpr size_t ZWORDS = O_END - O_ZERO;
constexpr int    ZJOBS  = (int)((ZWORDS / 4 + 255) / 256);
constexpr int    NJOBS  = 641 + ZJOBS;

typedef __attribute__((ext_vector_type(8))) short bf16x8;
typedef __attribute__((ext_vector_type(4))) float f32x4;

__device__ inline unsigned short f2bf(float f) {   // RNE
    unsigned int u = __float_as_uint(f);
    unsigned int r = (u + 0x7fffu + ((u >> 16) & 1u)) >> 16;
    return (unsigned short)r;
}
__device__ inline float b2f(unsigned short u) {
    return __uint_as_float(((unsigned int)u) << 16);
}
__device__ inline float bflo(unsigned int u) { return __uint_as_float(u << 16); }
__device__ inline float bfhi(unsigned int u) { return __uint_as_float(u & 0xffff0000u); }

// ---------------- shared memory union (per-phase views) ----------------
union ShMem {
    struct {
        unsigned short As[64][40];
        unsigned short Bs[256][40];
        float kvs[256];
        float cvs[256];
    } g;                                   // gemm phase: 27648 B
    struct {
        float wlds[4][260];
        float slds[2][4][256];
        float red[4][4];
    } a;                                   // agg / csr phase: 12416 B
};

struct MegaParams {
    const float* x; const int* srcA; const int* dstA; const float* ea; const int* batch;
    const float* W0; const float* W1; const float* W2;
    const float* asc0; const float* adc0; const float* asc1; const float* adc1;
    const float* asc2; const float* adc2;
    const float* gam0; const float* bet0; const float* gam1; const float* bet1;
    const float* gam2; const float* bet2;
    const float* We0; const float* att_e0;
    unsigned short* hbuf; unsigned short* aggb; uint4* rec;
    unsigned short* Bt0; unsigned short* Bt1; unsigned short* Bt2;
    float* asA; float* adA; float* Mb; int* deg; float* slsum; float* part;
    float* out;
};

// ---------------- gemm tile (64 rows x 256 cols), fused BN-in / att-dots ----
template <int K, bool NORM>
__device__ __forceinline__ void dev_gemm(ShMem* sh, int tile,
        const float* Af, const unsigned short* Ab, const unsigned short* Bt,
        const float* part, const float* gamma, const float* beta,
        const float* att_src, const float* att_dst,
        unsigned short* Hout, float* asA, float* adA) {
    int tid = threadIdx.x;
    int wave = tid >> 6, lane = tid & 63;
    int quad = lane >> 4, l16 = lane & 15;
    int row0 = tile * 64;
    f32x4 acc[4][4] = {};

    if (NORM) {        // inline bnfin from previous layer's partials
        int ch = tid;
        float s = 0.f, s2 = 0.f;
        #pragma unroll
        for (int b = 0; b < NB; ++b) {
            s  += part[b * 512 + ch];
            s2 += part[b * 512 + 256 + ch];
        }
        const float invN = 1.0f / (float)NN;
        float mr = s * invN;
        float var = s2 * invN - mr * mr;
        float k = gamma[ch] * rsqrtf(var + 1e-5f);
        sh->g.kvs[ch] = k;
        sh->g.cvs[ch] = beta[ch] - mr * k;
        __syncthreads();
    }

    for (int k0 = 0; k0 < K; k0 += 32) {
        {
            int row = tid >> 2, seg = tid & 3;
            ushort4 o0 = make_ushort4(0, 0, 0, 0), o1 = o0;
            if (row0 + row < NN) {
                float u[8];
                if (NORM) {
                    uint4 raw = *(const uint4*)(Ab + (size_t)(row0 + row) * K + k0 + seg * 8);
                    u[0] = bflo(raw.x); u[1] = bfhi(raw.x);
                    u[2] = bflo(raw.y); u[3] = bfhi(raw.y);
                    u[4] = bflo(raw.z); u[5] = bfhi(raw.z);
                    u[6] = bflo(raw.w); u[7] = bfhi(raw.w);
                    int cb = k0 + seg * 8;
                    #pragma unroll
                    for (int q = 0; q < 8; ++q)
                        u[q] = fmaxf(fmaf(u[q], sh->g.kvs[cb + q], sh->g.cvs[cb + q]), 0.f);
                } else {
                    const float* ap = Af + (size_t)(row0 + row) * K + k0 + seg * 8;
                    float4 f1 = *(const float4*)ap;
                    float4 f2 = *(const float4*)(ap + 4);
                    u[0] = f1.x; u[1] = f1.y; u[2] = f1.z; u[3] = f1.w;
                    u[4] = f2.x; u[5] = f2.y; u[6] = f2.z; u[7] = f2.w;
                }
                o0 = make_ushort4(f2bf(u[0]), f2bf(u[1]), f2bf(u[2]), f2bf(u[3]));
                o1 = make_ushort4(f2bf(u[4]), f2bf(u[5]), f2bf(u[6]), f2bf(u[7]));
            }
            *(ushort4*)&sh->g.As[row][seg * 8] = o0;
            *(ushort4*)&sh->g.As[row][seg * 8 + 4] = o1;
        }
        {
            const uint4* src = (const uint4*)(Bt + (size_t)tid * K + k0);
            uint4 b0 = src[0], b1 = src[1], b2 = src[2], b3 = src[3];
            uint4* dst = (uint4*)&sh->g.Bs[tid][0];
            dst[0] = b0; dst[1] = b1; dst[2] = b2; dst[3] = b3;
        }
        __syncthreads();
        bf16x8 a_frag[4], b_frag[4];
        #pragma unroll
        for (int mi = 0; mi < 4; ++mi)
            a_frag[mi] = *(const bf16x8*)&sh->g.As[mi * 16 + l16][quad * 8];
        #pragma unroll
        for (int ni = 0; ni < 4; ++ni)
            b_frag[ni] = *(const bf16x8*)&sh->g.Bs[wave * 64 + ni * 16 + l16][quad * 8];
        #pragma unroll
        for (int mi = 0; mi < 4; ++mi)
            #pragma unroll
            for (int ni = 0; ni < 4; ++ni)
                acc[mi][ni] = __builtin_amdgcn_mfma_f32_16x16x32_bf16(
                    a_frag[mi], b_frag[ni], acc[mi][ni], 0, 0, 0);
        __syncthreads();
    }

    #pragma unroll
    for (int mi = 0; mi < 4; ++mi) {
        #pragma unroll
        for (int reg = 0; reg < 4; ++reg) {
            int r = row0 + mi * 16 + quad * 4 + reg;
            if (r < NN) {
                #pragma unroll
                for (int ni = 0; ni < 4; ++ni) {
                    int c = wave * 64 + ni * 16 + l16;
                    Hout[(size_t)r * HCC + c] = f2bf(acc[mi][ni][reg]);
                }
            }
        }
    }
    float asc[4], adc_[4];
    #pragma unroll
    for (int ni = 0; ni < 4; ++ni) {
        asc[ni] = att_src[wave * 64 + ni * 16 + l16];
        adc_[ni] = att_dst[wave * 64 + ni * 16 + l16];
    }
    #pragma unroll
    for (int mi = 0; mi < 4; ++mi) {
        #pragma unroll
        for (int reg = 0; reg < 4; ++reg) {
            float s1 = acc[mi][0][reg] * asc[0] + acc[mi][1][reg] * asc[1] +
                       acc[mi][2][reg] * asc[2] + acc[mi][3][reg] * asc[3];
            float d1 = acc[mi][0][reg] * adc_[0] + acc[mi][1][reg] * adc_[1] +
                       acc[mi][2][reg] * adc_[2] + acc[mi][3][reg] * adc_[3];
            #pragma unroll
            for (int off = 1; off < 16; off <<= 1) {
                s1 += __shfl_xor(s1, off);
                d1 += __shfl_xor(d1, off);
            }
            int r = row0 + mi * 16 + quad * 4 + reg;
            if (l16 == 0 && r < NN) {
                asA[(size_t)r * 4 + wave] = s1;
                adA[(size_t)r * 4 + wave] = d1;
            }
        }
    }
}

// ---------------- agg for one node (per wave), R13 depth-1 pipeline ---------
template <bool HAS_AE>
__device__ __forceinline__ void dev_agg(float* wldsw, int n, int lane, int head,
        const unsigned short* Hm, const float* asA, const float* adA,
        const uint4* rec, const int* degA, const float* slsum,
        unsigned short* outA, float4& ssum, float4& sssq) {
    int st = n * CAP;
    int d = degA[n];
    if (d > CAP) d = CAP;
    float4 ad4 = *(const float4*)(adA + (size_t)n * 4);

    float4 w4 = make_float4(0.f, 0.f, 0.f, 0.f);
    int ms = 0;
    if (lane < d) {
        uint4 r = rec[st + lane];
        ms = (int)r.z;
        float4 av = *(const float4*)(asA + (size_t)ms * 4);
        float4 t = make_float4(av.x + ad4.x, av.y + ad4.y, av.z + ad4.z, av.w + ad4.w);
        if (HAS_AE) {
            if (r.w) {
                const float inv = 1.0f / (float)NE;
                t.x += slsum[0] * inv; t.y += slsum[1] * inv;
                t.z += slsum[2] * inv; t.w += slsum[3] * inv;
            } else {
                t.x += bflo(r.x); t.y += bfhi(r.x);
                t.z += bflo(r.y); t.w += bfhi(r.y);
            }
        }
        t.x = (t.x > 0.f) ? t.x : 0.2f * t.x;
        t.y = (t.y > 0.f) ? t.y : 0.2f * t.y;
        t.z = (t.z > 0.f) ? t.z : 0.2f * t.z;
        t.w = (t.w > 0.f) ? t.w : 0.2f * t.w;
        w4.x = __expf(t.x);
        w4.y = __expf(t.y);
        w4.z = __expf(t.z);
        w4.w = __expf(t.w);
    }
    float4 Dv = w4;
    wldsw[0 * 65 + lane] = w4.x;
    wldsw[1 * 65 + lane] = w4.y;
    wldsw[2 * 65 + lane] = w4.z;
    wldsw[3 * 65 + lane] = w4.w;

    float4 acc = make_float4(0.f, 0.f, 0.f, 0.f);
    const unsigned short* hb = Hm + lane * 4;
    int cnt8 = (d + 7) & ~7;
    const float* wrow = &wldsw[head * 65];

    ushort4 hvA[8];
    #pragma unroll
    for (int q = 0; q < 8; ++q) {
        int sj = __builtin_amdgcn_readlane(ms, q);
        hvA[q] = *(const ushort4*)(hb + (size_t)sj * HCC);
    }
    for (int jj = 0; jj < cnt8; jj += 8) {
        bool more = (jj + 8 < cnt8);
        ushort4 hvB[8];
        if (more) {
            #pragma unroll
            for (int q = 0; q < 8; ++q) {
                int sj = __builtin_amdgcn_readlane(ms, jj + 8 + q);
                hvB[q] = *(const ushort4*)(hb + (size_t)sj * HCC);
            }
        }
        float wq[8];
        #pragma unroll
        for (int q = 0; q < 8; ++q)
            wq[q] = wrow[jj + q];
        #pragma unroll
        for (int q = 0; q < 8; ++q) {
            acc.x = fmaf(wq[q], b2f(hvA[q].x), acc.x);
            acc.y = fmaf(wq[q], b2f(hvA[q].y), acc.y);
            acc.z = fmaf(wq[q], b2f(hvA[q].z), acc.z);
            acc.w = fmaf(wq[q], b2f(hvA[q].w), acc.w);
        }
        if (more) {
            #pragma unroll
            for (int q = 0; q < 8; ++q)
                hvA[q] = hvB[q];
        }
    }
    #pragma unroll
    for (int off = 32; off; off >>= 1) {
        Dv.x += __shfl_xor(Dv.x, off);
        Dv.y += __shfl_xor(Dv.y, off);
        Dv.z += __shfl_xor(Dv.z, off);
        Dv.w += __shfl_xor(Dv.w, off);
    }
    float D = (head & 2) ? ((head & 1) ? Dv.w : Dv.z) : ((head & 1) ? Dv.y : Dv.x);
    float inv = 1.0f / (D + 1e-16f);
    float4 o = make_float4(acc.x * inv, acc.y * inv, acc.z * inv, acc.w * inv);
    ushort4 ob = make_ushort4(f2bf(o.x), f2bf(o.y), f2bf(o.z), f2bf(o.w));
    *(ushort4*)(outA + (size_t)n * HCC + lane * 4) = ob;
    ssum.x += o.x; ssum.y += o.y; ssum.z += o.z; ssum.w += o.w;
    sssq.x = fmaf(o.x, o.x, sssq.x);
    sssq.y = fmaf(o.y, o.y, sssq.y);
    sssq.z = fmaf(o.z, o.z, sssq.z);
    sssq.w = fmaf(o.w, o.w, sssq.w);
}

// agg phase over grid-strided nodes + one stat-atomic set per block
template <bool HAS_AE>
__device__ __forceinline__ void agg_phase(ShMem* sh, const MegaParams& p, float* partL) {
    int tid = threadIdx.x;
    int wave = tid >> 6, lane = tid & 63, head = lane >> 4;
    int totalWaves = gridDim.x * 4;
    float4 ssum = make_float4(0.f, 0.f, 0.f, 0.f);
    float4 sssq = make_float4(0.f, 0.f, 0.f, 0.f);
    for (int n = blockIdx.x * 4 + wave; n < NN; n += totalWaves)
        dev_agg<HAS_AE>(sh->a.wlds[wave], n, lane, head, p.hbuf, p.asA, p.adA,
                        p.rec, p.deg, p.slsum, p.aggb, ssum, sssq);
    *(float4*)&sh->a.slds[0][wave][lane * 4] = ssum;
    *(float4*)&sh->a.slds[1][wave][lane * 4] = sssq;
    __syncthreads();
    int ch = tid;
    float s = sh->a.slds[0][0][ch] + sh->a.slds[0][1][ch] +
              sh->a.slds[0][2][ch] + sh->a.slds[0][3][ch];
    float s2 = sh->a.slds[1][0][ch] + sh->a.slds[1][1][ch] +
               sh->a.slds[1][2][ch] + sh->a.slds[1][3][ch];
    int bucket = blockIdx.x & (NB - 1);
    atomicAdd(&partL[bucket * 512 + ch], s);
    atomicAdd(&partL[bucket * 512 + 256 + ch], s2);
}

// ---------------- the single cooperative kernel ----------------
__global__ __launch_bounds__(256, 4) void mega_kernel(MegaParams p) {
    __shared__ ShMem sh;
    cg::grid_group grid = cg::this_grid();
    int tid = threadIdx.x;
    int wave = tid >> 6, lane = tid & 63;

    // ---- phase 1: Bt conversion + M + zero zone ----
    for (int job = blockIdx.x; job < NJOBS; job += gridDim.x) {
        if (job < 640) {
            const float* W; unsigned short* Bt; int K, base;
            if (job < 128)      { W = p.W0; Bt = p.Bt0; K = 128; base = 0; }
            else if (job < 384) { W = p.W1; Bt = p.Bt1; K = 256; base = 128; }
            else                { W = p.W2; Bt = p.Bt2; K = 256; base = 384; }
            int idx = (job - base) * 256 + tid;
            int nn = idx & 255, k = idx >> 8;
            Bt[(size_t)nn * K + k] = f2bf(W[(size_t)k * 256 + nn]);
        } else if (job == 640) {
            if (tid < 64) {
                int k = tid >> 2, hh = tid & 3;
                float s = 0.f;
                for (int c = 0; c < 64; ++c)
                    s += p.We0[k * 256 + hh * 64 + c] * p.att_e0[hh * 64 + c];
                p.Mb[k * 4 + hh] = s;
            }
        } else {
            size_t idx = ((size_t)(job - 641) * 256 + tid) * 4;
            float* zbase = (float*)p.deg;   // O_DEG == O_ZERO
            if (idx < ZWORDS)
                *(float4*)(zbase + idx) = make_float4(0.f, 0.f, 0.f, 0.f);
        }
    }
    grid.sync();

    // ---- phase 2: fused CSR build + edge logits ----
    {
        float a0 = 0.f, a1 = 0.f, a2 = 0.f, a3 = 0.f;
        for (int e = blockIdx.x * 256 + tid; e < ET; e += gridDim.x * 256) {
            bool real = (e < NE);
            int d = real ? p.dstA[e] : (e - NE);
            int s = real ? p.srcA[e] : (e - NE);
            int pp = atomicAdd(&p.deg[d], 1);
            if (pp > CAP - 1) pp = CAP - 1;
            int slot = d * CAP + pp;
            uint4 r;
            r.z = (unsigned)s;
            if (real) {
                r.w = 0u;
                const float4* q4 = (const float4*)(p.ea + (size_t)e * 16);
                float4 va = q4[0], vb = q4[1], vc = q4[2], vd = q4[3];
                float v[16] = {va.x, va.y, va.z, va.w, vb.x, vb.y, vb.z, vb.w,
                               vc.x, vc.y, vc.z, vc.w, vd.x, vd.y, vd.z, vd.w};
                float o0 = 0.f, o1 = 0.f, o2 = 0.f, o3 = 0.f;
                #pragma unroll
                for (int k = 0; k < 16; ++k) {
                    float4 m4 = *(const float4*)(p.Mb + k * 4);
                    o0 = fmaf(v[k], m4.x, o0);
                    o1 = fmaf(v[k], m4.y, o1);
                    o2 = fmaf(v[k], m4.z, o2);
                    o3 = fmaf(v[k], m4.w, o3);
                }
                r.x = ((unsigned)f2bf(o1) << 16) | (unsigned)f2bf(o0);
                r.y = ((unsigned)f2bf(o3) << 16) | (unsigned)f2bf(o2);
                a0 += o0; a1 += o1; a2 += o2; a3 += o3;
            } else {
                r.x = 0u; r.y = 0u; r.w = 1u;
            }
            p.rec[slot] = r;
        }
        #pragma unroll
        for (int off = 32; off; off >>= 1) {
            a0 += __shfl_xor(a0, off);
            a1 += __shfl_xor(a1, off);
            a2 += __shfl_xor(a2, off);
            a3 += __shfl_xor(a3, off);
        }
        if (lane == 0) {
            sh.a.red[wave][0] = a0; sh.a.red[wave][1] = a1;
            sh.a.red[wave][2] = a2; sh.a.red[wave][3] = a3;
        }
        __syncthreads();
        if (tid < 4)
            atomicAdd(&p.slsum[tid], sh.a.red[0][tid] + sh.a.red[1][tid] +
                                     sh.a.red[2][tid] + sh.a.red[3][tid]);
    }
    grid.sync();

    // ---- layer 0 ----
    for (int tile = blockIdx.x; tile < 782; tile += gridDim.x)
        dev_gemm<128, false>(&sh, tile, p.x, (const unsigned short*)0, p.Bt0,
                             (const float*)0, p.gam0, p.bet0, p.asc0, p.adc0,
                             p.hbuf, p.asA, p.adA);
    grid.sync();
    agg_phase<true>(&sh, p, p.part);
    grid.sync();

    // ---- layer 1 ----
    for (int tile = blockIdx.x; tile < 782; tile += gridDim.x)
        dev_gemm<256, true>(&sh, tile, (const float*)0, p.aggb, p.Bt1,
                            p.part, p.gam0, p.bet0, p.asc1, p.adc1,
                            p.hbuf, p.asA, p.adA);
    grid.sync();
    agg_phase<false>(&sh, p, p.part + (size_t)NB * 512);
    grid.sync();

    // ---- layer 2 ----
    for (int tile = blockIdx.x; tile < 782; tile += gridDim.x)
        dev_gemm<256, true>(&sh, tile, (const float*)0, p.aggb, p.Bt2,
                            p.part + (size_t)NB * 512, p.gam1, p.bet1, p.asc2, p.adc2,
                            p.hbuf, p.asA, p.adA);
    grid.sync();
    agg_phase<false>(&sh, p, p.part + (size_t)2 * NB * 512);
    grid.sync();

    // ---- pool: one block per group (batch sorted) ----
    if (blockIdx.x < GG) {
        int ch = tid;
        int g = blockIdx.x;
        const float* partL = p.part + (size_t)2 * NB * 512;
        float s = 0.f, s2 = 0.f;
        #pragma unroll
        for (int b = 0; b < NB; ++b) {
            s  += partL[b * 512 + ch];
            s2 += partL[b * 512 + 256 + ch];
        }
        const float invN = 1.0f / (float)NN;
        float mr = s * invN;
        float var = s2 * invN - mr * mr;
        float k = p.gam2[ch] * rsqrtf(var + 1e-5f);
        float c = p.bet2[ch] - mr * k;

        int lo = 0, hi = NN;
        while (lo < hi) { int mid = (lo + hi) >> 1; if (p.batch[mid] < g) lo = mid + 1; else hi = mid; }
        int start = lo;
        lo = start; hi = NN;
        while (lo < hi) { int mid = (lo + hi) >> 1; if (p.batch[mid] < g + 1) lo = mid + 1; else hi = mid; }
        int end = lo;

        float a0 = 0.f, a1 = 0.f, a2 = 0.f, a3 = 0.f;
        int n = start;
        for (; n + 3 < end; n += 4) {
            a0 += fmaxf(fmaf(b2f(p.aggb[(size_t)n * HCC + ch]), k, c), 0.f);
            a1 += fmaxf(fmaf(b2f(p.aggb[(size_t)(n + 1) * HCC + ch]), k, c), 0.f);
            a2 += fmaxf(fmaf(b2f(p.aggb[(size_t)(n + 2) * HCC + ch]), k, c), 0.f);
            a3 += fmaxf(fmaf(b2f(p.aggb[(size_t)(n + 3) * HCC + ch]), k, c), 0.f);
        }
        for (; n < end; ++n)
            a0 += fmaxf(fmaf(b2f(p.aggb[(size_t)n * HCC + ch]), k, c), 0.f);
        float tot = (a0 + a1) + (a2 + a3);
        p.out[(size_t)g * HCC + ch] = tot / fmaxf((float)(end - start), 1.0f);
    }
}

// ---------------- launch ----------------
extern "C" void kernel_launch(void* const* d_in, const int* in_sizes, int n_in,
                              void* d_out, int out_size, void* d_ws, size_t ws_size,
                              hipStream_t stream) {
    const float* x = (const float*)d_in[0];
    const int* edge_index = (const int*)d_in[1];
    const float* edge_attr = (const float*)d_in[2];
    const int* batch = (const int*)d_in[3];
    float* wsf = (float*)d_ws;

    MegaParams p;
    p.x = x;
    p.srcA = edge_index;
    p.dstA = edge_index + NE;
    p.ea = edge_attr;
    p.batch = batch;
    p.W0 = (const float*)d_in[4];  p.W1 = (const float*)d_in[10]; p.W2 = (const float*)d_in[16];
    p.asc0 = (const float*)d_in[5];  p.adc0 = (const float*)d_in[6];
    p.asc1 = (const float*)d_in[11]; p.adc1 = (const float*)d_in[12];
    p.asc2 = (const float*)d_in[17]; p.adc2 = (const float*)d_in[18];
    p.gam0 = (const float*)d_in[8];  p.bet0 = (const float*)d_in[9];
    p.gam1 = (const float*)d_in[14]; p.bet1 = (const float*)d_in[15];
    p.gam2 = (const float*)d_in[20]; p.bet2 = (const float*)d_in[21];
    p.We0 = (const float*)d_in[22];
    p.att_e0 = (const float*)d_in[23];
    p.hbuf = (unsigned short*)(wsf + O_H);
    p.aggb = (unsigned short*)(wsf + O_AGG);
    p.rec  = (uint4*)(wsf + O_REC);
    p.Bt0  = (unsigned short*)(wsf + O_BT0);
    p.Bt1  = (unsigned short*)(wsf + O_BT1);
    p.Bt2  = (unsigned short*)(wsf + O_BT2);
    p.asA  = wsf + O_AS;
    p.adA  = wsf + O_AD;
    p.Mb   = wsf + O_M;
    p.deg  = (int*)(wsf + O_DEG);
    p.slsum= wsf + O_SLS;
    p.part = wsf + O_PART;
    p.out  = (float*)d_out;

    int per = 0;
    hipOccupancyMaxActiveBlocksPerMultiprocessor(&per, mega_kernel, 256, 0);
    if (per < 1) per = 1;
    if (per > 8) per = 8;
    dim3 grid(per * 256), block(256);
    void* args[] = { (void*)&p };
    hipLaunchCooperativeKernel((const void*)mega_kernel, grid, block, args, 0, stream);
}

// Round 17
// 535.325 us; speedup vs baseline: 2.2802x; 2.2802x over previous
//
#include <hip/hip_runtime.h>
#include <math.h>

#define NN 50000
#define NE 800000
#define ET 850000   // NE + NN self loops
#define HCC 256     // H*C
#define GG 256
#define CAP 64      // fixed bucket capacity per node (P(deg>64) ~ 1e-14)
#define NB 16       // BN stat buckets

// ---------------- workspace layout (float-element offsets) ----------------
constexpr size_t NHC    = (size_t)NN * HCC;          // 12,800,000
constexpr size_t O_H    = 0;                         // bf16 h [NN,256]
constexpr size_t O_AGG  = O_H + NHC / 2;             // bf16 agg [NN,256]
constexpr size_t O_REC  = O_AGG + NHC / 2;           // uint4 rec [NN*64] (16B each)
constexpr size_t O_BT0  = O_REC + (size_t)NN * CAP * 4; // bf16 Bt0 [256,128]
constexpr size_t O_BT1  = O_BT0 + 16384;             // bf16 Bt1 [256,256]
constexpr size_t O_BT2  = O_BT1 + 32768;             // bf16 Bt2 [256,256]
constexpr size_t O_AS   = O_BT2 + 32768;             // [NN,4]
constexpr size_t O_AD   = O_AS + (size_t)NN * 4;     // [NN,4]
constexpr size_t O_M    = O_AD + (size_t)NN * 4;     // [16,4]
// ---- zero zone (zeroed by prep_kernel's tail blocks) ----
constexpr size_t O_ZERO = O_M + 64;
constexpr size_t O_DEG  = O_ZERO;                    // int [NN] bucket counters
constexpr size_t O_SLS  = O_DEG + NN;                // [4] self-loop logit sum
constexpr size_t O_PART = O_SLS + 4;                 // [3][NB][512] BN partials
constexpr size_t O_END  = O_PART + 3 * NB * 512;
constexpr size_t ZWORDS = O_END - O_ZERO;
constexpr int    ZBLK   = (int)((ZWORDS / 4 + 255) / 256);

typedef __attribute__((ext_vector_type(8))) short bf16x8;
typedef __attribute__((ext_vector_type(4))) float f32x4;

__device__ inline unsigned short f2bf(float f) {   // RNE
    unsigned int u = __float_as_uint(f);
    unsigned int r = (u + 0x7fffu + ((u >> 16) & 1u)) >> 16;
    return (unsigned short)r;
}
__device__ inline float b2f(unsigned short u) {
    return __uint_as_float(((unsigned int)u) << 16);
}
__device__ inline float bflo(unsigned int u) { return __uint_as_float(u << 16); }
__device__ inline float bfhi(unsigned int u) { return __uint_as_float(u & 0xffff0000u); }

// ---------------- prep: W->Bt (0..639) + M (640) + zero zone (641..) --------
__global__ void prep_kernel(const float* __restrict__ W0, const float* __restrict__ W1,
                            const float* __restrict__ W2,
                            const float* __restrict__ We0, const float* __restrict__ att_e0,
                            unsigned short* __restrict__ Bt0,
                            unsigned short* __restrict__ Bt1,
                            unsigned short* __restrict__ Bt2,
                            float* __restrict__ M, float* __restrict__ zbase) {
    int b = blockIdx.x;
    if (b >= 641) {
        size_t idx = ((size_t)(b - 641) * 256 + threadIdx.x) * 4;
        if (idx < ZWORDS)
            *(float4*)(zbase + idx) = make_float4(0.f, 0.f, 0.f, 0.f);
        return;
    }
    if (b == 640) {
        int t = threadIdx.x;
        if (t < 64) {
            int k = t >> 2, hh = t & 3;
            float s = 0.f;
            for (int c = 0; c < 64; ++c)
                s += We0[k * 256 + hh * 64 + c] * att_e0[hh * 64 + c];
            M[k * 4 + hh] = s;
        }
        return;
    }
    const float* W; unsigned short* Bt; int K, base;
    if (b < 128)      { W = W0; Bt = Bt0; K = 128; base = 0; }
    else if (b < 384) { W = W1; Bt = Bt1; K = 256; base = 128; }
    else              { W = W2; Bt = Bt2; K = 256; base = 384; }
    int idx = (b - base) * 256 + threadIdx.x;
    int n = idx & 255, k = idx >> 8;
    Bt[(size_t)n * K + k] = f2bf(W[(size_t)k * 256 + n]);
}

// ---------------- fused CSR build + edge logits (one pass, 16 edges/thread) -
// Record (16B): x=(l1|l0) bf16x2, y=(l3|l2) bf16x2, z=src, w=self-loop flag.
__global__ void csr_kernel(const int* __restrict__ srcA, const int* __restrict__ dstA,
                           const float* __restrict__ ea, const float* __restrict__ M,
                           int* __restrict__ deg, uint4* __restrict__ rec,
                           float* __restrict__ slsum) {
    int t0 = blockIdx.x * 4096 + threadIdx.x;
    float a0 = 0.f, a1 = 0.f, a2 = 0.f, a3 = 0.f;
    #pragma unroll
    for (int q = 0; q < 16; ++q) {
        int e = t0 + q * 256;
        if (e < ET) {
            bool real = (e < NE);
            int d = real ? dstA[e] : (e - NE);
            int s = real ? srcA[e] : (e - NE);
            int p = atomicAdd(&deg[d], 1);
            if (p > CAP - 1) p = CAP - 1;   // astronomically improbable guard
            int slot = d * CAP + p;
            uint4 r;
            r.z = (unsigned)s;
            if (real) {
                r.w = 0u;
                const float4* pp = (const float4*)(ea + (size_t)e * 16);
                float4 va = pp[0], vb = pp[1], vc = pp[2], vd = pp[3];
                float v[16] = {va.x, va.y, va.z, va.w, vb.x, vb.y, vb.z, vb.w,
                               vc.x, vc.y, vc.z, vc.w, vd.x, vd.y, vd.z, vd.w};
                float o0 = 0.f, o1 = 0.f, o2 = 0.f, o3 = 0.f;
                #pragma unroll
                for (int k = 0; k < 16; ++k) {
                    float4 m4 = *(const float4*)(M + k * 4);
                    o0 = fmaf(v[k], m4.x, o0);
                    o1 = fmaf(v[k], m4.y, o1);
                    o2 = fmaf(v[k], m4.z, o2);
                    o3 = fmaf(v[k], m4.w, o3);
                }
                r.x = ((unsigned)f2bf(o1) << 16) | (unsigned)f2bf(o0);
                r.y = ((unsigned)f2bf(o3) << 16) | (unsigned)f2bf(o2);
                a0 += o0; a1 += o1; a2 += o2; a3 += o3;
            } else {
                r.x = 0u; r.y = 0u; r.w = 1u;   // self-loop: logits patched in agg
            }
            rec[slot] = r;
        }
    }
    // block-reduce logit sums for the self-loop mean
    #pragma unroll
    for (int off = 32; off; off >>= 1) {
        a0 += __shfl_xor(a0, off);
        a1 += __shfl_xor(a1, off);
        a2 += __shfl_xor(a2, off);
        a3 += __shfl_xor(a3, off);
    }
    __shared__ float part[4][4];
    int wave = threadIdx.x >> 6, lane = threadIdx.x & 63;
    if (lane == 0) {
        part[wave][0] = a0; part[wave][1] = a1;
        part[wave][2] = a2; part[wave][3] = a3;
    }
    __syncthreads();
    if (threadIdx.x < 4)
        atomicAdd(&slsum[threadIdx.x],
                  part[0][threadIdx.x] + part[1][threadIdx.x] +
                  part[2][threadIdx.x] + part[3][threadIdx.x]);
}

// ---------------- fused GEMM: H = norm?(A) @ Bt^T, + per-head att dots ------
// NORM layers compute BN constants inline from the previous layer's partials.
template <int K, bool NORM>
__global__ __launch_bounds__(256) void gemm_fused(const float* __restrict__ Af,
                                                  const unsigned short* __restrict__ Ab,
                                                  const unsigned short* __restrict__ Bt,
                                                  const float* __restrict__ part,
                                                  const float* __restrict__ gamma,
                                                  const float* __restrict__ beta,
                                                  const float* __restrict__ att_src,
                                                  const float* __restrict__ att_dst,
                                                  unsigned short* __restrict__ Hout,
                                                  float* __restrict__ asA,
                                                  float* __restrict__ adA, int M) {
    __shared__ unsigned short As[64][40];    // pad 40 -> 80B row stride
    __shared__ unsigned short Bs[256][40];
    __shared__ float kvs[256], cvs[256];
    int tid = threadIdx.x;
    int wave = tid >> 6, lane = tid & 63;
    int quad = lane >> 4, l16 = lane & 15;
    int row0 = blockIdx.x * 64;
    f32x4 acc[4][4] = {};                    // [mi][ni]

    if (NORM) {        // inline bnfin: reduce NB buckets for this channel
        int ch = tid;
        float s = 0.f, s2 = 0.f;
        #pragma unroll
        for (int b = 0; b < NB; ++b) {
            s  += part[b * 512 + ch];
            s2 += part[b * 512 + 256 + ch];
        }
        const float invN = 1.0f / (float)NN;
        float mr = s * invN;
        float var = s2 * invN - mr * mr;
        float k = gamma[ch] * rsqrtf(var + 1e-5f);
        kvs[ch] = k;
        cvs[ch] = beta[ch] - mr * k;
        __syncthreads();
    }

    for (int k0 = 0; k0 < K; k0 += 32) {
        // stage A: 64 rows x 32 k; thread -> row tid>>2, 8-ch segment tid&3
        {
            int row = tid >> 2, seg = tid & 3;
            ushort4 o0 = make_ushort4(0, 0, 0, 0), o1 = o0;
            if (row0 + row < M) {
                float u[8];
                if (NORM) {
                    uint4 raw = *(const uint4*)(Ab + (size_t)(row0 + row) * K + k0 + seg * 8);
                    u[0] = bflo(raw.x); u[1] = bfhi(raw.x);
                    u[2] = bflo(raw.y); u[3] = bfhi(raw.y);
                    u[4] = bflo(raw.z); u[5] = bfhi(raw.z);
                    u[6] = bflo(raw.w); u[7] = bfhi(raw.w);
                    int cb = k0 + seg * 8;
                    #pragma unroll
                    for (int q = 0; q < 8; ++q)
                        u[q] = fmaxf(fmaf(u[q], kvs[cb + q], cvs[cb + q]), 0.f);
                } else {
                    const float* ap = Af + (size_t)(row0 + row) * K + k0 + seg * 8;
                    float4 f1 = *(const float4*)ap;
                    float4 f2 = *(const float4*)(ap + 4);
                    u[0] = f1.x; u[1] = f1.y; u[2] = f1.z; u[3] = f1.w;
                    u[4] = f2.x; u[5] = f2.y; u[6] = f2.z; u[7] = f2.w;
                }
                o0 = make_ushort4(f2bf(u[0]), f2bf(u[1]), f2bf(u[2]), f2bf(u[3]));
                o1 = make_ushort4(f2bf(u[4]), f2bf(u[5]), f2bf(u[6]), f2bf(u[7]));
            }
            *(ushort4*)&As[row][seg * 8] = o0;
            *(ushort4*)&As[row][seg * 8 + 4] = o1;
        }
        // stage B^T: 256 cols x 32 k; thread -> col tid (64B)
        {
            const uint4* src = (const uint4*)(Bt + (size_t)tid * K + k0);
            uint4 b0 = src[0], b1 = src[1], b2 = src[2], b3 = src[3];
            uint4* dst = (uint4*)&Bs[tid][0];
            dst[0] = b0; dst[1] = b1; dst[2] = b2; dst[3] = b3;
        }
        __syncthreads();
        bf16x8 a_frag[4], b_frag[4];
        #pragma unroll
        for (int mi = 0; mi < 4; ++mi)
            a_frag[mi] = *(const bf16x8*)&As[mi * 16 + l16][quad * 8];
        #pragma unroll
        for (int ni = 0; ni < 4; ++ni)
            b_frag[ni] = *(const bf16x8*)&Bs[wave * 64 + ni * 16 + l16][quad * 8];
        #pragma unroll
        for (int mi = 0; mi < 4; ++mi)
            #pragma unroll
            for (int ni = 0; ni < 4; ++ni)
                acc[mi][ni] = __builtin_amdgcn_mfma_f32_16x16x32_bf16(
                    a_frag[mi], b_frag[ni], acc[mi][ni], 0, 0, 0);
        __syncthreads();
    }

    // epilogue 1: H bf16 (C/D layout: col=lane&15, row=quad*4+reg)
    #pragma unroll
    for (int mi = 0; mi < 4; ++mi) {
        #pragma unroll
        for (int reg = 0; reg < 4; ++reg) {
            int r = row0 + mi * 16 + quad * 4 + reg;
            if (r < M) {
                #pragma unroll
                for (int ni = 0; ni < 4; ++ni) {
                    int c = wave * 64 + ni * 16 + l16;
                    Hout[(size_t)r * HCC + c] = f2bf(acc[mi][ni][reg]);
                }
            }
        }
    }
    // epilogue 2: per-head attention dots (head = wave)
    float asc[4], adc_[4];
    #pragma unroll
    for (int ni = 0; ni < 4; ++ni) {
        asc[ni] = att_src[wave * 64 + ni * 16 + l16];
        adc_[ni] = att_dst[wave * 64 + ni * 16 + l16];
    }
    #pragma unroll
    for (int mi = 0; mi < 4; ++mi) {
        #pragma unroll
        for (int reg = 0; reg < 4; ++reg) {
            float s1 = acc[mi][0][reg] * asc[0] + acc[mi][1][reg] * asc[1] +
                       acc[mi][2][reg] * asc[2] + acc[mi][3][reg] * asc[3];
            float d1 = acc[mi][0][reg] * adc_[0] + acc[mi][1][reg] * adc_[1] +
                       acc[mi][2][reg] * adc_[2] + acc[mi][3][reg] * adc_[3];
            #pragma unroll
            for (int off = 1; off < 16; off <<= 1) {
                s1 += __shfl_xor(s1, off);
                d1 += __shfl_xor(d1, off);
            }
            int r = row0 + mi * 16 + quad * 4 + reg;
            if (l16 == 0 && r < M) {
                asA[(size_t)r * 4 + wave] = s1;
                adA[(size_t)r * 4 + wave] = d1;
            }
        }
    }
}

// ---------------- fused softmax aggregation + BN partial stats --------------
// 8 waves/block (8 nodes); depth-1 prefetched gather; bucket-major atomics.
template <bool HAS_AE>
__global__ __launch_bounds__(512) void agg_kernel(const unsigned short* __restrict__ Hm,
                                                  const float* __restrict__ asA,
                                                  const float* __restrict__ adA,
                                                  const uint4* __restrict__ rec,
                                                  const int* __restrict__ degA,
                                                  const float* __restrict__ slsum,
                                                  unsigned short* __restrict__ outA,
                                                  float* __restrict__ part) {
    __shared__ float wlds[8][260];       // [wave][head*65 + j]
    __shared__ float slds[2][8][256];    // [sum/ssq][wave][ch]
    int wave = threadIdx.x >> 6, lane = threadIdx.x & 63;
    int n = blockIdx.x * 8 + wave;       // grid exact: 6250*8 == NN
    int head = lane >> 4;
    int st = n * CAP;
    int d = degA[n];
    if (d > CAP) d = CAP;
    float4 ad4 = *(const float4*)(adA + (size_t)n * 4);

    float4 w4 = make_float4(0.f, 0.f, 0.f, 0.f);
    int ms = 0;
    if (lane < d) {
        uint4 r = rec[st + lane];
        ms = (int)r.z;
        float4 av = *(const float4*)(asA + (size_t)ms * 4);
        float4 t = make_float4(av.x + ad4.x, av.y + ad4.y, av.z + ad4.z, av.w + ad4.w);
        if (HAS_AE) {
            if (r.w) {   // self-loop: mean edge logit via linearity
                const float inv = 1.0f / (float)NE;
                t.x += slsum[0] * inv; t.y += slsum[1] * inv;
                t.z += slsum[2] * inv; t.w += slsum[3] * inv;
            } else {
                t.x += bflo(r.x); t.y += bfhi(r.x);
                t.z += bflo(r.y); t.w += bfhi(r.y);
            }
        }
        t.x = (t.x > 0.f) ? t.x : 0.2f * t.x;
        t.y = (t.y > 0.f) ? t.y : 0.2f * t.y;
        t.z = (t.z > 0.f) ? t.z : 0.2f * t.z;
        t.w = (t.w > 0.f) ? t.w : 0.2f * t.w;
        w4.x = __expf(t.x);
        w4.y = __expf(t.y);
        w4.z = __expf(t.z);
        w4.w = __expf(t.w);
    }
    float4 Dv = w4;
    wlds[wave][0 * 65 + lane] = w4.x;
    wlds[wave][1 * 65 + lane] = w4.y;
    wlds[wave][2 * 65 + lane] = w4.z;
    wlds[wave][3 * 65 + lane] = w4.w;

    float4 acc = make_float4(0.f, 0.f, 0.f, 0.f);
    const unsigned short* hb = Hm + lane * 4;
    int cnt8 = (d + 7) & ~7;             // >= 8 (self-loop guarantees d >= 1)
    const float* wrow = &wlds[wave][head * 65];

    // depth-1 software-pipelined gather: group jj+8's loads issue before
    // group jj's FMAs consume.
    ushort4 hvA[8];
    #pragma unroll
    for (int q = 0; q < 8; ++q) {
        int sj = __builtin_amdgcn_readlane(ms, q);
        hvA[q] = *(const ushort4*)(hb + (size_t)sj * HCC);
    }
    for (int jj = 0; jj < cnt8; jj += 8) {
        bool more = (jj + 8 < cnt8);
        ushort4 hvB[8];
        if (more) {
            #pragma unroll
            for (int q = 0; q < 8; ++q) {
                int sj = __builtin_amdgcn_readlane(ms, jj + 8 + q);
                hvB[q] = *(const ushort4*)(hb + (size_t)sj * HCC);
            }
        }
        float wq[8];
        #pragma unroll
        for (int q = 0; q < 8; ++q)
            wq[q] = wrow[jj + q];        // LDS broadcast per head
        #pragma unroll
        for (int q = 0; q < 8; ++q) {
            acc.x = fmaf(wq[q], b2f(hvA[q].x), acc.x);
            acc.y = fmaf(wq[q], b2f(hvA[q].y), acc.y);
            acc.z = fmaf(wq[q], b2f(hvA[q].z), acc.z);
            acc.w = fmaf(wq[q], b2f(hvA[q].w), acc.w);
        }
        if (more) {
            #pragma unroll
            for (int q = 0; q < 8; ++q)
                hvA[q] = hvB[q];
        }
    }
    #pragma unroll
    for (int off = 32; off; off >>= 1) {
        Dv.x += __shfl_xor(Dv.x, off);
        Dv.y += __shfl_xor(Dv.y, off);
        Dv.z += __shfl_xor(Dv.z, off);
        Dv.w += __shfl_xor(Dv.w, off);
    }
    float D = (head & 2) ? ((head & 1) ? Dv.w : Dv.z) : ((head & 1) ? Dv.y : Dv.x);
    float inv = 1.0f / (D + 1e-16f);
    float4 o = make_float4(acc.x * inv, acc.y * inv, acc.z * inv, acc.w * inv);
    ushort4 ob = make_ushort4(f2bf(o.x), f2bf(o.y), f2bf(o.z), f2bf(o.w));
    *(ushort4*)(outA + (size_t)n * HCC + lane * 4) = ob;

    // fused BN partials: block-reduce 8 nodes, bucket-major coalesced atomics
    *(float4*)&slds[0][wave][lane * 4] = o;
    *(float4*)&slds[1][wave][lane * 4] =
        make_float4(o.x * o.x, o.y * o.y, o.z * o.z, o.w * o.w);
    __syncthreads();
    int t = threadIdx.x;
    int ch = t & 255, which = t >> 8;
    float s = 0.f;
    #pragma unroll
    for (int w = 0; w < 8; ++w)
        s += slds[which][w][ch];
    int bucket = blockIdx.x & (NB - 1);
    atomicAdd(&part[bucket * 512 + which * 256 + ch], s);
}

// ---------------- pooling: one block per group (batch sorted), direct out ---
__global__ void pool_kernel(const unsigned short* __restrict__ aggb,
                            const float* __restrict__ part,
                            const float* __restrict__ gamma, const float* __restrict__ beta,
                            const int* __restrict__ batch,
                            float* __restrict__ out) {
    int ch = threadIdx.x;
    int g = blockIdx.x;
    float s = 0.f, s2 = 0.f;
    #pragma unroll
    for (int b = 0; b < NB; ++b) {
        s  += part[b * 512 + ch];
        s2 += part[b * 512 + 256 + ch];
    }
    const float invN = 1.0f / (float)NN;
    float mr = s * invN;
    float var = s2 * invN - mr * mr;
    float k = gamma[ch] * rsqrtf(var + 1e-5f);
    float c = beta[ch] - mr * k;

    // group bounds via binary search (batch sorted ascending)
    int lo = 0, hi = NN;
    while (lo < hi) { int mid = (lo + hi) >> 1; if (batch[mid] < g) lo = mid + 1; else hi = mid; }
    int start = lo;
    lo = start; hi = NN;
    while (lo < hi) { int mid = (lo + hi) >> 1; if (batch[mid] < g + 1) lo = mid + 1; else hi = mid; }
    int end = lo;

    float a0 = 0.f, a1 = 0.f, a2 = 0.f, a3 = 0.f;
    int n = start;
    for (; n + 3 < end; n += 4) {
        a0 += fmaxf(fmaf(b2f(aggb[(size_t)n * HCC + ch]), k, c), 0.f);
        a1 += fmaxf(fmaf(b2f(aggb[(size_t)(n + 1) * HCC + ch]), k, c), 0.f);
        a2 += fmaxf(fmaf(b2f(aggb[(size_t)(n + 2) * HCC + ch]), k, c), 0.f);
        a3 += fmaxf(fmaf(b2f(aggb[(size_t)(n + 3) * HCC + ch]), k, c), 0.f);
    }
    for (; n < end; ++n)
        a0 += fmaxf(fmaf(b2f(aggb[(size_t)n * HCC + ch]), k, c), 0.f);
    float tot = (a0 + a1) + (a2 + a3);
    out[(size_t)g * HCC + ch] = tot / fmaxf((float)(end - start), 1.0f);
}

// ---------------- launch ----------------
extern "C" void kernel_launch(void* const* d_in, const int* in_sizes, int n_in,
                              void* d_out, int out_size, void* d_ws, size_t ws_size,
                              hipStream_t stream) {
    const float* x = (const float*)d_in[0];
    const int* edge_index = (const int*)d_in[1];
    const int* srcA = edge_index;
    const int* dstA = edge_index + NE;
    const float* edge_attr = (const float*)d_in[2];
    const int* batch = (const int*)d_in[3];
    const float* W[3]   = {(const float*)d_in[4],  (const float*)d_in[10], (const float*)d_in[16]};
    const float* asc[3] = {(const float*)d_in[5],  (const float*)d_in[11], (const float*)d_in[17]};
    const float* adc[3] = {(const float*)d_in[6],  (const float*)d_in[12], (const float*)d_in[18]};
    const float* gam[3] = {(const float*)d_in[8],  (const float*)d_in[14], (const float*)d_in[20]};
    const float* bet[3] = {(const float*)d_in[9],  (const float*)d_in[15], (const float*)d_in[21]};
    const float* We0 = (const float*)d_in[22];
    const float* att_e0 = (const float*)d_in[23];

    float* wsf = (float*)d_ws;
    unsigned short* hbuf = (unsigned short*)(wsf + O_H);
    unsigned short* aggb = (unsigned short*)(wsf + O_AGG);
    uint4* rec   = (uint4*)(wsf + O_REC);
    unsigned short* Bt0  = (unsigned short*)(wsf + O_BT0);
    unsigned short* Bt1  = (unsigned short*)(wsf + O_BT1);
    unsigned short* Bt2  = (unsigned short*)(wsf + O_BT2);
    float* asA   = wsf + O_AS;
    float* adA   = wsf + O_AD;
    float* Mb    = wsf + O_M;
    int*   deg   = (int*)(wsf + O_DEG);
    float* slsum = wsf + O_SLS;
    float* part  = wsf + O_PART;

    // prep: W->bf16 Bt, M, and zeroing of deg/slsum/part (replaces memset)
    prep_kernel<<<641 + ZBLK, 256, 0, stream>>>(W[0], W[1], W[2], We0, att_e0,
                                                Bt0, Bt1, Bt2, Mb, wsf + O_ZERO);
    csr_kernel<<<(ET + 4095) / 4096, 256, 0, stream>>>(srcA, dstA, edge_attr, Mb,
                                                       deg, rec, slsum);

    unsigned short* Bts[3] = {Bt0, Bt1, Bt2};
    for (int L = 0; L < 3; ++L) {
        if (L == 0)
            gemm_fused<128, false><<<782, 256, 0, stream>>>(x, (const unsigned short*)0,
                Bts[0], (const float*)0, gam[0], bet[0], asc[0], adc[0], hbuf, asA, adA, NN);
        else
            gemm_fused<256, true><<<782, 256, 0, stream>>>((const float*)0, aggb,
                Bts[L], part + (size_t)(L - 1) * NB * 512, gam[L - 1], bet[L - 1],
                asc[L], adc[L], hbuf, asA, adA, NN);
        if (L == 0)
            agg_kernel<true><<<6250, 512, 0, stream>>>(hbuf, asA, adA, rec, deg, slsum,
                aggb, part + (size_t)L * NB * 512);
        else
            agg_kernel<false><<<6250, 512, 0, stream>>>(hbuf, asA, adA, rec, deg, slsum,
                aggb, part + (size_t)L * NB * 512);
    }

    pool_kernel<<<GG, 256, 0, stream>>>(aggb, part + (size_t)2 * NB * 512,
                                        gam[2], bet[2], batch, (float*)d_out);
}